// Round 1
// baseline (5050.267 us; speedup 1.0000x reference)
//
#include <hip/hip_runtime.h>

#define BB 128
#define NPTS 20000
#define NSTEP 4
#define NITER 4

// ws float offsets
#define OFF_ANCHOR 0
#define OFF_G      384
#define OFF_AO     400
#define OFF_U      2448
#define OFF_XL     67984
#define OFF_OUT    133520
#define OFF_H      166288
#define OFF_C      231824
#define OFF_GB     297360
#define OFF_RMN    428432
#define OFF_TM     461200
#define OFF_TV     493968

// d_out float offsets
#define OUT_VAR   7680
#define OUT_VIEWS 15360

__device__ __forceinline__ float sigf(float x){ return 1.0f/(1.0f+expf(-x)); }

__device__ __forceinline__ float blockSum256(float v, float* buf){
    for (int off = 32; off > 0; off >>= 1) v += __shfl_down(v, off, 64);
    int tid = threadIdx.x;
    __syncthreads();
    if ((tid & 63) == 0) buf[tid >> 6] = v;
    __syncthreads();
    return (buf[0] + buf[1]) + (buf[2] + buf[3]);
}

__device__ __forceinline__ double blockSum256d(double v, double* buf){
    for (int off = 32; off > 0; off >>= 1) v += __shfl_down(v, off, 64);
    int tid = threadIdx.x;
    __syncthreads();
    if ((tid & 63) == 0) buf[tid >> 6] = v;
    __syncthreads();
    return (buf[0] + buf[1]) + (buf[2] + buf[3]);
}

// ---------------- init ----------------
__global__ __launch_bounds__(256) void k_init(const float* __restrict__ inp, float* __restrict__ ws)
{
    int i = blockIdx.x*256 + threadIdx.x;
    if (i < BB*3) ws[OFF_ANCHOR + i] = inp[i];
}

// Precompute per-step G (2x2) and Ao (256x2) with fp64 accumulation.
__global__ __launch_bounds__(256) void k_pre(const float* __restrict__ Wq, const float* __restrict__ Wk,
                                             const float* __restrict__ Wv, const float* __restrict__ Win,
                                             const float* __restrict__ Wout, float* __restrict__ ws)
{
    __shared__ float wql[512], wkl[512], wvl[512];
    __shared__ double avl[512];
    __shared__ double dbuf[4];
    int s = blockIdx.x, t = threadIdx.x;
    wql[t] = Wq[s*512 + t];   wql[256+t] = Wq[s*512 + 256 + t];
    wkl[t] = Wk[s*512 + t];   wkl[256+t] = Wk[s*512 + 256 + t];
    wvl[t] = Wv[s*512 + t];   wvl[256+t] = Wv[s*512 + 256 + t];
    __syncthreads();
    const float* wq = Win + s*196608 + t*256;
    const float* wk = wq + 65536;
    const float* wv = wq + 131072;
    double aq0=0,aq1=0,ak0=0,ak1=0,av0=0,av1=0;
    for (int j = 0; j < 256; j++){
        double a = wq[j], b = wk[j], c = wv[j];
        aq0 += a*(double)wql[j*2]; aq1 += a*(double)wql[j*2+1];
        ak0 += b*(double)wkl[j*2]; ak1 += b*(double)wkl[j*2+1];
        av0 += c*(double)wvl[j*2]; av1 += c*(double)wvl[j*2+1];
    }
    avl[t*2] = av0; avl[t*2+1] = av1;
    double g00 = blockSum256d(aq0*ak0, dbuf);
    double g01 = blockSum256d(aq0*ak1, dbuf);
    double g10 = blockSum256d(aq1*ak0, dbuf);
    double g11 = blockSum256d(aq1*ak1, dbuf);
    if (t == 0){
        ws[OFF_G + s*4+0] = (float)g00; ws[OFF_G + s*4+1] = (float)g01;
        ws[OFF_G + s*4+2] = (float)g10; ws[OFF_G + s*4+3] = (float)g11;
    }
    const float* wo = Wout + s*65536 + t*256;
    double o0 = 0.0, o1 = 0.0;
    for (int j = 0; j < 256; j++){
        double w = wo[j];
        o0 += w*avl[j*2]; o1 += w*avl[j*2+1];
    }
    ws[OFF_AO + s*512 + t*2]   = (float)o0;
    ws[OFF_AO + s*512 + t*2+1] = (float)o1;
}

// per-step: h=c=1, write pre_mean[.,s,0,:]=anchor, pre_var[.,s,0,:]=0.01
__global__ __launch_bounds__(256) void k_step_init(float* __restrict__ ws, float* __restrict__ out, int s)
{
    int gid = blockIdx.x*256 + threadIdx.x;
    if (gid < 2*BB*256){ ws[OFF_H + gid] = 1.0f; ws[OFF_C + gid] = 1.0f; }
    if (gid < BB*3){
        int b = gid/3, j = gid - b*3;
        out[((b*NSTEP + s)*5 + 0)*3 + j] = ws[OFF_ANCHOR + gid];
        out[OUT_VAR + ((b*NSTEP + s)*5 + 0)*3 + j] = 0.01f;
    }
}

// ---------------- map top-256 selection ----------------
__global__ __launch_bounds__(256) void k_map(const float* __restrict__ mp, float* __restrict__ ws,
                                             float* __restrict__ out, int s, int t)
{
    __shared__ unsigned int histx[2048], histy[2048];
    __shared__ float vx[1024], vy[1024];
    __shared__ float candx[1024], candy[1024];
    __shared__ int scanb[256];
    __shared__ int shjx, shjy;
    __shared__ unsigned int cnt_in, cntx, cnty;
    int tid = threadIdx.x, b = blockIdx.x;
    float ax = ws[OFF_ANCHOR + b*3 + 0];
    float ay = ws[OFF_ANCHOR + b*3 + 1];
    float th = ws[OFF_ANCHOR + b*3 + 2];
    float cth = cosf(th), sth = sinf(th);
    for (int i = tid; i < 2048; i += 256){ histx[i] = 0u; histy[i] = 0u; }
    if (tid == 0){ cnt_in = 0u; cntx = 0u; cnty = 0u; }
    __syncthreads();
    for (int i = tid; i < NPTS; i += 256){
        float dx = mp[i] - ax, dy = mp[NPTS + i] - ay;
        float rx = cth*dx + sth*dy;
        float ry = cth*dy - sth*dx;
        float d  = sqrtf(rx*rx + ry*ry);
        if (d < 10.0f){
            unsigned p = atomicAdd(&cnt_in, 1u);
            if (p < 1024u){ vx[p] = rx; vy[p] = ry; }
            int bx = (int)((rx + 10.0f) * 102.4f); bx = min(max(bx, 0), 2047);
            int by = (int)((ry + 10.0f) * 102.4f); by = min(max(by, 0), 2047);
            atomicAdd(&histx[bx], 1u); atomicAdd(&histy[by], 1u);
        }
    }
    __syncthreads();
    int total = (int)min(cnt_in, 1024u);
    int K = min(256, total);
    // cutoff bucket for x
    {
        int part = 0;
        for (int k = 0; k < 8; k++) part += (int)histx[tid*8 + k];
        scanb[tid] = part; __syncthreads();
        for (int off = 1; off < 256; off <<= 1){
            int v = (tid >= off) ? scanb[tid - off] : 0; __syncthreads();
            scanb[tid] += v; __syncthreads();
        }
        int incl = scanb[tid], excl = incl - part;
        if (K > 0 && excl < K && incl >= K){
            int c = excl;
            for (int k = 0; k < 8; k++){ c += (int)histx[tid*8+k]; if (c >= K){ shjx = tid*8+k; break; } }
        }
        if (K == 0 && tid == 0) shjx = -1;
        __syncthreads();
    }
    // cutoff bucket for y
    {
        int part = 0;
        for (int k = 0; k < 8; k++) part += (int)histy[tid*8 + k];
        scanb[tid] = part; __syncthreads();
        for (int off = 1; off < 256; off <<= 1){
            int v = (tid >= off) ? scanb[tid - off] : 0; __syncthreads();
            scanb[tid] += v; __syncthreads();
        }
        int incl = scanb[tid], excl = incl - part;
        if (K > 0 && excl < K && incl >= K){
            int c = excl;
            for (int k = 0; k < 8; k++){ c += (int)histy[tid*8+k]; if (c >= K){ shjy = tid*8+k; break; } }
        }
        if (K == 0 && tid == 0) shjy = -1;
        __syncthreads();
    }
    int jx = shjx, jy = shjy;
    for (int i = tid; i < total; i += 256){
        float v = vx[i];
        int bx = (int)((v + 10.0f)*102.4f); bx = min(max(bx,0),2047);
        if (bx <= jx){ unsigned p = atomicAdd(&cntx,1u); if (p < 1024u) candx[p] = v; }
        v = vy[i];
        int by = (int)((v + 10.0f)*102.4f); by = min(max(by,0),2047);
        if (by <= jy){ unsigned p = atomicAdd(&cnty,1u); if (p < 1024u) candy[p] = v; }
    }
    __syncthreads();
    int cx = (int)min(cntx, 1024u), cy = (int)min(cnty, 1024u);
    for (int i = tid; i < 1024; i += 256){
        if (i >= cx) candx[i] = 3.0e38f;
        if (i >= cy) candy[i] = 3.0e38f;
    }
    __syncthreads();
    // bitonic sort (1024 elems, both arrays)
    for (int k = 2; k <= 1024; k <<= 1){
        for (int j = k >> 1; j > 0; j >>= 1){
            for (int q = 0; q < 4; q++){
                int i = q*256 + tid;
                int ixj = i ^ j;
                if (ixj > i){
                    bool up = ((i & k) == 0);
                    float a = candx[i], b2 = candx[ixj];
                    if ((a > b2) == up){ candx[i] = b2; candx[ixj] = a; }
                    a = candy[i]; b2 = candy[ixj];
                    if ((a > b2) == up){ candy[i] = b2; candy[ixj] = a; }
                }
            }
            __syncthreads();
        }
    }
    int obase = OUT_VIEWS + (((b*NSTEP + s)*5 + t)*2)*256;
    out[obase + tid]       = (tid < K) ? candx[tid] : 0.0f;
    out[obase + 256 + tid] = (tid < K) ? candy[tid] : 0.0f;
}

// ---------------- enc_a -> LN -> xl[:,0:256] ----------------
__global__ __launch_bounds__(256) void k_enc(float* __restrict__ ws, const float* __restrict__ Wenc,
                                             const float* __restrict__ endp, int s)
{
    __shared__ float rbuf[4];
    int b = blockIdx.x, t = threadIdx.x;
    float a0 = ws[OFF_ANCHOR + b*3+0], a1 = ws[OFF_ANCHOR + b*3+1], a2 = ws[OFF_ANCHOR + b*3+2];
    float z[9] = {a0, a1, a2, a0-endp[0], a1-endp[1], a2-endp[2], 0.01f, 0.01f, 0.01f};
    const float* w = Wenc + s*2304 + t*9;
    float acc = 0.f;
    #pragma unroll
    for (int j = 0; j < 9; j++) acc += z[j]*w[j];
    float mu = blockSum256(acc, rbuf) * (1.0f/256.0f);
    float d = acc - mu;
    float var = blockSum256(d*d, rbuf) * (1.0f/256.0f);
    ws[OFF_XL + b*512 + t] = d * rsqrtf(var + 1e-5f);
}

// ---------------- attention (rank-2 collapsed) -> u (B,256,2) ----------------
__global__ __launch_bounds__(256) void k_attn(const float* __restrict__ out, float* __restrict__ ws, int s, int t)
{
    __shared__ float mlx[256], mly[256];
    int b = blockIdx.x, i = threadIdx.x;
    int obase = OUT_VIEWS + (((b*NSTEP + s)*5 + t)*2)*256;
    mlx[i] = out[obase + i];
    mly[i] = out[obase + 256 + i];
    __syncthreads();
    float g00 = ws[OFF_G + s*4+0], g01 = ws[OFF_G + s*4+1];
    float g10 = ws[OFF_G + s*4+2], g11 = ws[OFF_G + s*4+3];
    float x = mlx[i], y = mly[i];
    float t0 = g00*x + g10*y;
    float t1 = g01*x + g11*y;
    float mx = -1e30f;
    for (int j = 0; j < 256; j++){
        float l = (t0*mlx[j] + t1*mly[j]) * 0.0625f;
        mx = fmaxf(mx, l);
    }
    float sum = 0.f, ux = 0.f, uy = 0.f;
    for (int j = 0; j < 256; j++){
        float l = (t0*mlx[j] + t1*mly[j]) * 0.0625f;
        float e = expf(l - mx);
        sum += e; ux += e*mlx[j]; uy += e*mly[j];
    }
    float inv = 1.0f/sum;
    ws[OFF_U + b*512 + i*2]   = ux*inv;
    ws[OFF_U + b*512 + i*2+1] = uy*inv;
}

// ---------------- fused relu(X)@W_map1^T -> relu -> @w2 -> outmap ----------------
__device__ __forceinline__ int swx(int r, int mf){ return r*32 + ((mf ^ (r & 7)) << 2); }
__device__ __forceinline__ int sww(int c, int mf){ return c*32 + ((mf ^ ((c >> 2) & 7)) << 2); }

__global__ __launch_bounds__(256) void k_big(float* __restrict__ ws, const float* __restrict__ W1,
                                             const float* __restrict__ W2, int s)
{
    __shared__ __align__(16) float ul[512];
    __shared__ float aol[128];
    __shared__ float w2l[256];
    __shared__ __align__(16) float xt[2048];
    __shared__ __align__(16) float w1t[2048];
    __shared__ float red[64*17];
    int st = blockIdx.x, b = blockIdx.y;
    int tid = threadIdx.x, tx = tid & 15, ty = tid >> 4;
    {
        float2 uv = *(const float2*)(ws + OFF_U + b*512 + tid*2);
        ul[tid*2] = uv.x; ul[tid*2+1] = uv.y;
        if (tid < 128) aol[tid] = ws[OFF_AO + s*512 + st*128 + tid];
        w2l[tid] = W2[tid];
    }
    __syncthreads();
    float psum[4] = {0.f,0.f,0.f,0.f};
    for (int sct = 0; sct < 4; sct++){
        float acc[4][4];
        #pragma unroll
        for (int i=0;i<4;i++){
            #pragma unroll
            for (int j=0;j<4;j++) acc[i][j] = 0.f;
        }
        for (int mt = 0; mt < 8; mt++){
            {
                int cl = tid >> 2, f0 = tid & 3;
                const float* g = W1 + (sct*64 + cl)*256 + mt*32 + f0*4;
                float4 v0 = *(const float4*)g;
                float4 v1 = *(const float4*)(g + 16);
                *(float4*)(w1t + sww(cl, f0))   = v0;
                *(float4*)(w1t + sww(cl, f0+4)) = v1;
            }
            {
                int r = tid >> 2, mg = tid & 3;
                float A0 = aol[r*2], A1 = aol[r*2+1];
                int m0 = mt*32 + mg*4;
                float4 o0, o1;
                o0.x = fmaxf(A0*ul[(m0+0)*2] + A1*ul[(m0+0)*2+1], 0.f);
                o0.y = fmaxf(A0*ul[(m0+1)*2] + A1*ul[(m0+1)*2+1], 0.f);
                o0.z = fmaxf(A0*ul[(m0+2)*2] + A1*ul[(m0+2)*2+1], 0.f);
                o0.w = fmaxf(A0*ul[(m0+3)*2] + A1*ul[(m0+3)*2+1], 0.f);
                int m1 = mt*32 + (mg+4)*4;
                o1.x = fmaxf(A0*ul[(m1+0)*2] + A1*ul[(m1+0)*2+1], 0.f);
                o1.y = fmaxf(A0*ul[(m1+1)*2] + A1*ul[(m1+1)*2+1], 0.f);
                o1.z = fmaxf(A0*ul[(m1+2)*2] + A1*ul[(m1+2)*2+1], 0.f);
                o1.w = fmaxf(A0*ul[(m1+3)*2] + A1*ul[(m1+3)*2+1], 0.f);
                *(float4*)(xt + swx(r, mg))   = o0;
                *(float4*)(xt + swx(r, mg+4)) = o1;
            }
            __syncthreads();
            #pragma unroll
            for (int m4 = 0; m4 < 8; m4++){
                float4 xv[4], wv[4];
                #pragma unroll
                for (int i=0;i<4;i++) xv[i] = *(const float4*)(xt + swx(ty*4+i, m4));
                #pragma unroll
                for (int j=0;j<4;j++) wv[j] = *(const float4*)(w1t + sww(tx*4+j, m4));
                #pragma unroll
                for (int i=0;i<4;i++){
                    #pragma unroll
                    for (int j=0;j<4;j++){
                        acc[i][j] += xv[i].x*wv[j].x + xv[i].y*wv[j].y + xv[i].z*wv[j].z + xv[i].w*wv[j].w;
                    }
                }
            }
            __syncthreads();
        }
        #pragma unroll
        for (int i=0;i<4;i++){
            #pragma unroll
            for (int j=0;j<4;j++){
                psum[i] += fmaxf(acc[i][j], 0.f) * w2l[sct*64 + tx*4 + j];
            }
        }
    }
    #pragma unroll
    for (int i=0;i<4;i++) red[(ty*4+i)*17 + tx] = psum[i];
    __syncthreads();
    if (tid < 64){
        float sm = 0.f;
        #pragma unroll
        for (int q=0;q<16;q++) sm += red[tid*17 + q];
        ws[OFF_OUT + b*256 + st*64 + tid] = sm;
    }
}

// LN(outmap) -> xl[:,256:512]
__global__ __launch_bounds__(256) void k_lnencm(float* __restrict__ ws)
{
    __shared__ float rbuf[4];
    int b = blockIdx.x, t = threadIdx.x;
    float v = ws[OFF_OUT + b*256 + t];
    float mu = blockSum256(v, rbuf) * (1.0f/256.0f);
    float d = v - mu;
    float var = blockSum256(d*d, rbuf) * (1.0f/256.0f);
    ws[OFF_XL + b*512 + 256 + t] = d * rsqrtf(var + 1e-5f);
}

// ---------------- generic small GEMM: C[b,o] = (RELU?)( A1@W1^T (+ A2@W2^T) ) ----------------
template<int K>
__device__ __forceinline__ void gemm_pass(const float* __restrict__ A, const float* __restrict__ W,
                                          float* As, float* Wsh, float (&acc)[2][4],
                                          int bt, int ot, int tid)
{
    int tx = tid & 15, ty = tid >> 4;
    for (int kt = 0; kt < K/32; kt++){
        {
            int bb = tid >> 3, kk = (tid & 7) * 4;
            float4 v = *(const float4*)(A + (bt*32+bb)*K + kt*32 + kk);
            float* ap = As + bb*33 + kk;
            ap[0]=v.x; ap[1]=v.y; ap[2]=v.z; ap[3]=v.w;
        }
        {
            int oo = tid >> 2, kk = (tid & 3) * 8;
            const float* g = W + (ot*64+oo)*K + kt*32 + kk;
            float4 v0 = *(const float4*)g;
            float4 v1 = *(const float4*)(g + 4);
            float* wp = Wsh + oo*33 + kk;
            wp[0]=v0.x; wp[1]=v0.y; wp[2]=v0.z; wp[3]=v0.w;
            wp[4]=v1.x; wp[5]=v1.y; wp[6]=v1.z; wp[7]=v1.w;
        }
        __syncthreads();
        #pragma unroll
        for (int kk = 0; kk < 32; kk++){
            float a0 = As[(ty*2)*33 + kk], a1 = As[(ty*2+1)*33 + kk];
            float w0 = Wsh[(tx*4)*33+kk],   w1 = Wsh[(tx*4+1)*33+kk];
            float w2 = Wsh[(tx*4+2)*33+kk], w3 = Wsh[(tx*4+3)*33+kk];
            acc[0][0] += a0*w0; acc[0][1] += a0*w1; acc[0][2] += a0*w2; acc[0][3] += a0*w3;
            acc[1][0] += a1*w0; acc[1][1] += a1*w1; acc[1][2] += a1*w2; acc[1][3] += a1*w3;
        }
        __syncthreads();
    }
}

template<int K1, int K2, int RELU>
__global__ __launch_bounds__(256) void k_gemm(const float* __restrict__ A1, const float* __restrict__ W1,
                                              const float* __restrict__ A2, const float* __restrict__ W2,
                                              float* __restrict__ C, int Osz)
{
    __shared__ float As[32*33];
    __shared__ float Wsh[64*33];
    int tid = threadIdx.x, tx = tid & 15, ty = tid >> 4;
    int ot = blockIdx.x, bt = blockIdx.y;
    float acc[2][4];
    #pragma unroll
    for (int i=0;i<2;i++){
        #pragma unroll
        for (int j=0;j<4;j++) acc[i][j]=0.f;
    }
    gemm_pass<K1>(A1, W1, As, Wsh, acc, bt, ot, tid);
    if constexpr (K2 > 0){
        gemm_pass<K2>(A2, W2, As, Wsh, acc, bt, ot, tid);
    }
    #pragma unroll
    for (int i=0;i<2;i++){
        float4 v;
        v.x = acc[i][0]; v.y = acc[i][1]; v.z = acc[i][2]; v.w = acc[i][3];
        if (RELU){ v.x=fmaxf(v.x,0.f); v.y=fmaxf(v.y,0.f); v.z=fmaxf(v.z,0.f); v.w=fmaxf(v.w,0.f); }
        *(float4*)(C + (bt*32+ty*2+i)*Osz + ot*64 + tx*4) = v;
    }
}

// ---------------- LSTM gate elementwise ----------------
__global__ __launch_bounds__(256) void k_gates(float* __restrict__ ws, int l)
{
    int b = blockIdx.x, t = threadIdx.x;
    const float* g = ws + OFF_GB + b*1024;
    float ig = g[t], fg = g[256+t], gg = g[512+t], og = g[768+t];
    int idx = l*BB*256 + b*256 + t;
    float cold = ws[OFF_C + idx];
    float cl = sigf(fg)*cold + sigf(ig)*tanhf(gg);
    float hl = sigf(og)*tanhf(cl);
    ws[OFF_C + idx] = cl;
    ws[OFF_H + idx] = hl;
}

// LN(h1) -> relu -> rmn
__global__ __launch_bounds__(256) void k_mn(float* __restrict__ ws)
{
    __shared__ float rbuf[4];
    int b = blockIdx.x, t = threadIdx.x;
    float v = ws[OFF_H + BB*256 + b*256 + t];
    float mu = blockSum256(v, rbuf) * (1.0f/256.0f);
    float d = v - mu;
    float var = blockSum256(d*d, rbuf) * (1.0f/256.0f);
    ws[OFF_RMN + b*256 + t] = fmaxf(d * rsqrtf(var + 1e-5f), 0.0f);
}

// heads: mean/var 3-vec each; updates anchor and writes outputs
__global__ __launch_bounds__(256) void k_head(const float* __restrict__ Wm2, const float* __restrict__ Wv2,
                                              const float* __restrict__ dlm, float* __restrict__ ws,
                                              float* __restrict__ out, int s, int t)
{
    int b = blockIdx.x, tid = threadIdx.x;
    int w = tid >> 6, lane = tid & 63;
    #pragma unroll
    for (int p = 0; p < 2; p++){
        int oi = p*4 + w;
        if (oi < 6){
            int j = (oi < 3) ? oi : oi - 3;
            const float* tb = ws + ((oi < 3) ? OFF_TM : OFF_TV) + b*256;
            const float* wr = ((oi < 3) ? Wm2 : Wv2) + j*256;
            float pa = 0.f;
            #pragma unroll
            for (int q = 0; q < 4; q++) pa += tb[lane + 64*q] * wr[lane + 64*q];
            for (int off = 32; off > 0; off >>= 1) pa += __shfl_down(pa, off, 64);
            if (lane == 0){
                if (oi < 3){
                    float mv = tanhf(pa) * dlm[j] + ws[OFF_ANCHOR + b*3 + j];
                    out[((b*NSTEP + s)*5 + (t+1))*3 + j] = mv;
                    ws[OFF_ANCHOR + b*3 + j] = mv;
                } else {
                    out[OUT_VAR + ((b*NSTEP + s)*5 + (t+1))*3 + j] = sigf(pa)*0.1f;
                }
            }
        }
    }
}

extern "C" void kernel_launch(void* const* d_in, const int* in_sizes, int n_in,
                              void* d_out, int out_size, void* d_ws, size_t ws_size,
                              hipStream_t stream)
{
    (void)in_sizes; (void)n_in; (void)out_size; (void)ws_size;
    const float* inp  = (const float*)d_in[0];
    const float* mp   = (const float*)d_in[1];
    const float* endp = (const float*)d_in[2];
    const float* dlm  = (const float*)d_in[3];
    const float* Wenc = (const float*)d_in[4];
    const float* Wq   = (const float*)d_in[5];
    const float* Wk   = (const float*)d_in[6];
    const float* Wv   = (const float*)d_in[7];
    const float* Win  = (const float*)d_in[8];
    const float* Wout = (const float*)d_in[9];
    const float* Wmap1= (const float*)d_in[10];
    const float* Wmap2= (const float*)d_in[11];
    const float* Wih0 = (const float*)d_in[12];
    const float* Wih1 = (const float*)d_in[13];
    const float* Whh0 = (const float*)d_in[14];
    const float* Whh1 = (const float*)d_in[15];
    const float* Wm1  = (const float*)d_in[16];
    const float* Wm2  = (const float*)d_in[17];
    const float* Wv1  = (const float*)d_in[18];
    const float* Wv2  = (const float*)d_in[19];
    float* out = (float*)d_out;
    float* ws  = (float*)d_ws;

    k_init<<<2, 256, 0, stream>>>(inp, ws);
    k_pre<<<NSTEP, 256, 0, stream>>>(Wq, Wk, Wv, Win, Wout, ws);
    for (int s = 0; s < NSTEP; s++){
        k_step_init<<<256, 256, 0, stream>>>(ws, out, s);
        for (int t = 0; t < NITER; t++){
            k_map<<<BB, 256, 0, stream>>>(mp, ws, out, s, t);
            k_enc<<<BB, 256, 0, stream>>>(ws, Wenc, endp, s);
            k_attn<<<BB, 256, 0, stream>>>(out, ws, s, t);
            k_big<<<dim3(4, BB), 256, 0, stream>>>(ws, Wmap1 + s*65536, Wmap2 + s*256, s);
            k_lnencm<<<BB, 256, 0, stream>>>(ws);
            k_gemm<512,256,0><<<dim3(16,4), 256, 0, stream>>>(ws+OFF_XL, Wih0 + s*524288,
                                                              ws+OFF_H,  Whh0 + s*262144,
                                                              ws+OFF_GB, 1024);
            k_gates<<<BB, 256, 0, stream>>>(ws, 0);
            k_gemm<256,256,0><<<dim3(16,4), 256, 0, stream>>>(ws+OFF_H,          Wih1 + s*262144,
                                                              ws+OFF_H + BB*256, Whh1 + s*262144,
                                                              ws+OFF_GB, 1024);
            k_gates<<<BB, 256, 0, stream>>>(ws, 1);
            k_mn<<<BB, 256, 0, stream>>>(ws);
            k_gemm<256,0,1><<<dim3(4,4), 256, 0, stream>>>(ws+OFF_RMN, Wm1 + s*65536,
                                                           nullptr, nullptr, ws+OFF_TM, 256);
            k_gemm<256,0,1><<<dim3(4,4), 256, 0, stream>>>(ws+OFF_RMN, Wv1 + s*65536,
                                                           nullptr, nullptr, ws+OFF_TV, 256);
            k_head<<<BB, 256, 0, stream>>>(Wm2 + s*768, Wv2 + s*768, dlm, ws, out, s, t);
        }
        k_map<<<BB, 256, 0, stream>>>(mp, ws, out, s, 4);
    }
}

// Round 2
// 4491.988 us; speedup vs baseline: 1.1243x; 1.1243x over previous
//
#include <hip/hip_runtime.h>

#define BB 128
#define NPTS 20000
#define NSTEP 4
#define NITER 4

// ws float offsets
#define OFF_ANCHOR 0
#define OFF_G      384
#define OFF_AO     400
#define OFF_U      2448
#define OFF_XL     67984
#define OFF_OUT    133520
#define OFF_H      166288
#define OFF_C      231824
#define OFF_GB     297360
#define OFF_RMN    428432
#define OFF_TM     461200
#define OFF_TV     493968

// d_out float offsets
#define OUT_VAR   7680
#define OUT_VIEWS 15360

__device__ __forceinline__ float sigf(float x){ return 1.0f/(1.0f+expf(-x)); }

__device__ __forceinline__ float blockSum256(float v, float* buf){
    for (int off = 32; off > 0; off >>= 1) v += __shfl_down(v, off, 64);
    int tid = threadIdx.x;
    __syncthreads();
    if ((tid & 63) == 0) buf[tid >> 6] = v;
    __syncthreads();
    return (buf[0] + buf[1]) + (buf[2] + buf[3]);
}

__device__ __forceinline__ double blockSum256d(double v, double* buf){
    for (int off = 32; off > 0; off >>= 1) v += __shfl_down(v, off, 64);
    int tid = threadIdx.x;
    __syncthreads();
    if ((tid & 63) == 0) buf[tid >> 6] = v;
    __syncthreads();
    return (buf[0] + buf[1]) + (buf[2] + buf[3]);
}

// ---------------- init ----------------
__global__ __launch_bounds__(256) void k_init(const float* __restrict__ inp, float* __restrict__ ws)
{
    int i = blockIdx.x*256 + threadIdx.x;
    if (i < BB*3) ws[OFF_ANCHOR + i] = inp[i];
}

// Precompute per-step G (2x2) and Ao (256x2) with fp64 accumulation.
__global__ __launch_bounds__(256) void k_pre(const float* __restrict__ Wq, const float* __restrict__ Wk,
                                             const float* __restrict__ Wv, const float* __restrict__ Win,
                                             const float* __restrict__ Wout, float* __restrict__ ws)
{
    __shared__ float wql[512], wkl[512], wvl[512];
    __shared__ double avl[512];
    __shared__ double dbuf[4];
    int s = blockIdx.x, t = threadIdx.x;
    wql[t] = Wq[s*512 + t];   wql[256+t] = Wq[s*512 + 256 + t];
    wkl[t] = Wk[s*512 + t];   wkl[256+t] = Wk[s*512 + 256 + t];
    wvl[t] = Wv[s*512 + t];   wvl[256+t] = Wv[s*512 + 256 + t];
    __syncthreads();
    const float* wq = Win + s*196608 + t*256;
    const float* wk = wq + 65536;
    const float* wv = wq + 131072;
    double aq0=0,aq1=0,ak0=0,ak1=0,av0=0,av1=0;
    for (int j = 0; j < 256; j++){
        double a = wq[j], b = wk[j], c = wv[j];
        aq0 += a*(double)wql[j*2]; aq1 += a*(double)wql[j*2+1];
        ak0 += b*(double)wkl[j*2]; ak1 += b*(double)wkl[j*2+1];
        av0 += c*(double)wvl[j*2]; av1 += c*(double)wvl[j*2+1];
    }
    avl[t*2] = av0; avl[t*2+1] = av1;
    double g00 = blockSum256d(aq0*ak0, dbuf);
    double g01 = blockSum256d(aq0*ak1, dbuf);
    double g10 = blockSum256d(aq1*ak0, dbuf);
    double g11 = blockSum256d(aq1*ak1, dbuf);
    if (t == 0){
        ws[OFF_G + s*4+0] = (float)g00; ws[OFF_G + s*4+1] = (float)g01;
        ws[OFF_G + s*4+2] = (float)g10; ws[OFF_G + s*4+3] = (float)g11;
    }
    const float* wo = Wout + s*65536 + t*256;
    double o0 = 0.0, o1 = 0.0;
    for (int j = 0; j < 256; j++){
        double w = wo[j];
        o0 += w*avl[j*2]; o1 += w*avl[j*2+1];
    }
    ws[OFF_AO + s*512 + t*2]   = (float)o0;
    ws[OFF_AO + s*512 + t*2+1] = (float)o1;
}

// per-step: h=c=1, write pre_mean[.,s,0,:]=anchor, pre_var[.,s,0,:]=0.01
__global__ __launch_bounds__(256) void k_step_init(float* __restrict__ ws, float* __restrict__ out, int s)
{
    int gid = blockIdx.x*256 + threadIdx.x;
    if (gid < 2*BB*256){ ws[OFF_H + gid] = 1.0f; ws[OFF_C + gid] = 1.0f; }
    if (gid < BB*3){
        int b = gid/3, j = gid - b*3;
        out[((b*NSTEP + s)*5 + 0)*3 + j] = ws[OFF_ANCHOR + gid];
        out[OUT_VAR + ((b*NSTEP + s)*5 + 0)*3 + j] = 0.01f;
    }
}

// ---------------- map top-256 selection (histogram cutoff + rank-select) ----------------
__global__ __launch_bounds__(256) void k_map(const float* __restrict__ mp, float* __restrict__ ws,
                                             float* __restrict__ out, int s, int t)
{
    __shared__ unsigned int histx[2048], histy[2048];
    __shared__ float vx[1024], vy[1024];
    __shared__ float candx[512], candy[512];
    __shared__ float sortx[256], sorty[256];
    __shared__ int scanb[256];
    __shared__ int shjx, shjy;
    __shared__ unsigned int cnt_in, cntx, cnty;
    int tid = threadIdx.x, b = blockIdx.x;
    float ax = ws[OFF_ANCHOR + b*3 + 0];
    float ay = ws[OFF_ANCHOR + b*3 + 1];
    float th = ws[OFF_ANCHOR + b*3 + 2];
    float cth = cosf(th), sth = sinf(th);
    for (int i = tid; i < 2048; i += 256){ histx[i] = 0u; histy[i] = 0u; }
    if (tid == 0){ cnt_in = 0u; cntx = 0u; cnty = 0u; }
    __syncthreads();
    for (int i = tid; i < NPTS; i += 256){
        float dx = mp[i] - ax, dy = mp[NPTS + i] - ay;
        float rx = cth*dx + sth*dy;
        float ry = cth*dy - sth*dx;
        float d  = sqrtf(rx*rx + ry*ry);
        if (d < 10.0f){
            unsigned p = atomicAdd(&cnt_in, 1u);
            if (p < 1024u){ vx[p] = rx; vy[p] = ry; }
            int bx = (int)((rx + 10.0f) * 102.4f); bx = min(max(bx, 0), 2047);
            int by = (int)((ry + 10.0f) * 102.4f); by = min(max(by, 0), 2047);
            atomicAdd(&histx[bx], 1u); atomicAdd(&histy[by], 1u);
        }
    }
    __syncthreads();
    int total = (int)min(cnt_in, 1024u);
    int K = min(256, total);
    // cutoff bucket for x
    {
        int part = 0;
        for (int k = 0; k < 8; k++) part += (int)histx[tid*8 + k];
        scanb[tid] = part; __syncthreads();
        for (int off = 1; off < 256; off <<= 1){
            int v = (tid >= off) ? scanb[tid - off] : 0; __syncthreads();
            scanb[tid] += v; __syncthreads();
        }
        int incl = scanb[tid], excl = incl - part;
        if (K > 0 && excl < K && incl >= K){
            int c = excl;
            for (int k = 0; k < 8; k++){ c += (int)histx[tid*8+k]; if (c >= K){ shjx = tid*8+k; break; } }
        }
        if (K == 0 && tid == 0) shjx = -1;
        __syncthreads();
    }
    // cutoff bucket for y
    {
        int part = 0;
        for (int k = 0; k < 8; k++) part += (int)histy[tid*8 + k];
        scanb[tid] = part; __syncthreads();
        for (int off = 1; off < 256; off <<= 1){
            int v = (tid >= off) ? scanb[tid - off] : 0; __syncthreads();
            scanb[tid] += v; __syncthreads();
        }
        int incl = scanb[tid], excl = incl - part;
        if (K > 0 && excl < K && incl >= K){
            int c = excl;
            for (int k = 0; k < 8; k++){ c += (int)histy[tid*8+k]; if (c >= K){ shjy = tid*8+k; break; } }
        }
        if (K == 0 && tid == 0) shjy = -1;
        __syncthreads();
    }
    int jx = shjx, jy = shjy;
    for (int i = tid; i < total; i += 256){
        float v = vx[i];
        int bx = (int)((v + 10.0f)*102.4f); bx = min(max(bx,0),2047);
        if (bx <= jx){ unsigned p = atomicAdd(&cntx,1u); if (p < 512u) candx[p] = v; }
        v = vy[i];
        int by = (int)((v + 10.0f)*102.4f); by = min(max(by,0),2047);
        if (by <= jy){ unsigned p = atomicAdd(&cnty,1u); if (p < 512u) candy[p] = v; }
    }
    __syncthreads();
    int cx = (int)min(cntx, 512u), cy = (int)min(cnty, 512u);
    // rank-by-counting: candidate i's rank = #{j : v_j < v_i or (v_j==v_i and j<i)}
    for (int i = tid; i < cx; i += 256){
        float v = candx[i];
        int r = 0;
        for (int j = 0; j < cx; j++){
            float w = candx[j];
            r += (w < v) || (w == v && j < i);
        }
        if (r < 256) sortx[r] = v;
    }
    for (int i = tid; i < cy; i += 256){
        float v = candy[i];
        int r = 0;
        for (int j = 0; j < cy; j++){
            float w = candy[j];
            r += (w < v) || (w == v && j < i);
        }
        if (r < 256) sorty[r] = v;
    }
    __syncthreads();
    int obase = OUT_VIEWS + (((b*NSTEP + s)*5 + t)*2)*256;
    out[obase + tid]       = (tid < K) ? sortx[tid] : 0.0f;
    out[obase + 256 + tid] = (tid < K) ? sorty[tid] : 0.0f;
}

// ---------------- fused: enc_a -> LN -> xl[0:256]  +  rank-2 attention -> u ----------------
__global__ __launch_bounds__(256) void k_encattn(const float* __restrict__ out, float* __restrict__ ws,
                                                 const float* __restrict__ Wenc, const float* __restrict__ endp,
                                                 int s, int t)
{
    __shared__ float rbuf[4];
    __shared__ float mlx[256], mly[256];
    int b = blockIdx.x, i = threadIdx.x;
    int obase = OUT_VIEWS + (((b*NSTEP + s)*5 + t)*2)*256;
    mlx[i] = out[obase + i];
    mly[i] = out[obase + 256 + i];
    // enc part
    float a0 = ws[OFF_ANCHOR + b*3+0], a1 = ws[OFF_ANCHOR + b*3+1], a2 = ws[OFF_ANCHOR + b*3+2];
    float z[9] = {a0, a1, a2, a0-endp[0], a1-endp[1], a2-endp[2], 0.01f, 0.01f, 0.01f};
    const float* w = Wenc + s*2304 + i*9;
    float acc = 0.f;
    #pragma unroll
    for (int j = 0; j < 9; j++) acc += z[j]*w[j];
    float mu = blockSum256(acc, rbuf) * (1.0f/256.0f);  // syncs inside make mlx/mly visible
    float d = acc - mu;
    float var = blockSum256(d*d, rbuf) * (1.0f/256.0f);
    ws[OFF_XL + b*512 + i] = d * rsqrtf(var + 1e-5f);
    // attn part
    float g00 = ws[OFF_G + s*4+0], g01 = ws[OFF_G + s*4+1];
    float g10 = ws[OFF_G + s*4+2], g11 = ws[OFF_G + s*4+3];
    float x = mlx[i], y = mly[i];
    float t0 = g00*x + g10*y;
    float t1 = g01*x + g11*y;
    float mx = -1e30f;
    for (int j = 0; j < 256; j++){
        float l = (t0*mlx[j] + t1*mly[j]) * 0.0625f;
        mx = fmaxf(mx, l);
    }
    float sum = 0.f, ux = 0.f, uy = 0.f;
    for (int j = 0; j < 256; j++){
        float l = (t0*mlx[j] + t1*mly[j]) * 0.0625f;
        float e = expf(l - mx);
        sum += e; ux += e*mlx[j]; uy += e*mly[j];
    }
    float inv = 1.0f/sum;
    ws[OFF_U + b*512 + i*2]   = ux*inv;
    ws[OFF_U + b*512 + i*2+1] = uy*inv;
}

// ---------------- fused relu(X)@W_map1^T -> relu -> @w2, partial over 64-j chunk ----------------
// grid (sct=4, st=4, b=128); partials land in OFF_GB (dead between iterations)
__global__ __launch_bounds__(256) void k_big(float* __restrict__ ws, const float* __restrict__ W1,
                                             const float* __restrict__ W2, int s)
{
    __shared__ __align__(16) float ul[512];
    __shared__ float aol[128];
    __shared__ float w2l[64];
    __shared__ __align__(16) float xt[64*36];
    __shared__ __align__(16) float w1t[64*36];
    __shared__ float red[64*17];
    int sct = blockIdx.x, st = blockIdx.y, b = blockIdx.z;
    int tid = threadIdx.x, tx = tid & 15, ty = tid >> 4;
    {
        float2 uv = *(const float2*)(ws + OFF_U + b*512 + tid*2);
        ul[tid*2] = uv.x; ul[tid*2+1] = uv.y;
        if (tid < 128) aol[tid] = ws[OFF_AO + s*512 + st*128 + tid];
        if (tid < 64)  w2l[tid] = W2[sct*64 + tid];
    }
    __syncthreads();
    float acc[4][4];
    #pragma unroll
    for (int i=0;i<4;i++){
        #pragma unroll
        for (int j=0;j<4;j++) acc[i][j] = 0.f;
    }
    for (int mt = 0; mt < 8; mt++){
        {
            int cl = tid >> 2, f0 = tid & 3;
            const float* g = W1 + (sct*64 + cl)*256 + mt*32 + f0*4;
            float4 v0 = *(const float4*)g;
            float4 v1 = *(const float4*)(g + 16);
            *(float4*)(w1t + cl*36 + f0*4)      = v0;
            *(float4*)(w1t + cl*36 + f0*4 + 16) = v1;
        }
        {
            int r = tid >> 2, mg = tid & 3;
            float A0 = aol[r*2], A1 = aol[r*2+1];
            int m0 = mt*32 + mg*4;
            float4 o0, o1;
            o0.x = fmaxf(A0*ul[(m0+0)*2] + A1*ul[(m0+0)*2+1], 0.f);
            o0.y = fmaxf(A0*ul[(m0+1)*2] + A1*ul[(m0+1)*2+1], 0.f);
            o0.z = fmaxf(A0*ul[(m0+2)*2] + A1*ul[(m0+2)*2+1], 0.f);
            o0.w = fmaxf(A0*ul[(m0+3)*2] + A1*ul[(m0+3)*2+1], 0.f);
            int m1 = mt*32 + (mg+4)*4;
            o1.x = fmaxf(A0*ul[(m1+0)*2] + A1*ul[(m1+0)*2+1], 0.f);
            o1.y = fmaxf(A0*ul[(m1+1)*2] + A1*ul[(m1+1)*2+1], 0.f);
            o1.z = fmaxf(A0*ul[(m1+2)*2] + A1*ul[(m1+2)*2+1], 0.f);
            o1.w = fmaxf(A0*ul[(m1+3)*2] + A1*ul[(m1+3)*2+1], 0.f);
            *(float4*)(xt + r*36 + mg*4)     = o0;
            *(float4*)(xt + r*36 + (mg+4)*4) = o1;
        }
        __syncthreads();
        #pragma unroll
        for (int m4 = 0; m4 < 8; m4++){
            float4 xv[4], wv[4];
            #pragma unroll
            for (int i=0;i<4;i++) xv[i] = *(const float4*)(xt + (ty*4+i)*36 + m4*4);
            #pragma unroll
            for (int j=0;j<4;j++) wv[j] = *(const float4*)(w1t + (tx + 16*j)*36 + m4*4);
            #pragma unroll
            for (int i=0;i<4;i++){
                #pragma unroll
                for (int j=0;j<4;j++){
                    acc[i][j] += xv[i].x*wv[j].x + xv[i].y*wv[j].y + xv[i].z*wv[j].z + xv[i].w*wv[j].w;
                }
            }
        }
        __syncthreads();
    }
    float psum[4];
    #pragma unroll
    for (int i=0;i<4;i++){
        float p = 0.f;
        #pragma unroll
        for (int j=0;j<4;j++) p += fmaxf(acc[i][j], 0.f) * w2l[tx + 16*j];
        psum[i] = p;
        red[(ty*4+i)*17 + tx] = p;
    }
    __syncthreads();
    if (tid < 64){
        float sm = 0.f;
        #pragma unroll
        for (int q=0;q<16;q++) sm += red[tid*17 + q];
        ws[OFF_GB + b*1024 + sct*256 + st*64 + tid] = sm;
    }
}

// sum 4 partials -> LN -> xl[:,256:512]
__global__ __launch_bounds__(256) void k_lnencm(float* __restrict__ ws)
{
    __shared__ float rbuf[4];
    int b = blockIdx.x, t = threadIdx.x;
    const float* p = ws + OFF_GB + b*1024;
    float v = ((p[t] + p[256+t]) + p[512+t]) + p[768+t];
    // match old order: sequential sct accumulate
    v = p[t];
    v += p[256+t]; v += p[512+t]; v += p[768+t];
    float mu = blockSum256(v, rbuf) * (1.0f/256.0f);
    float d = v - mu;
    float var = blockSum256(d*d, rbuf) * (1.0f/256.0f);
    ws[OFF_XL + b*512 + 256 + t] = d * rsqrtf(var + 1e-5f);
}

// ---------------- generic small GEMM: C[b,o] = (RELU?)( A1@W1^T (+ A2@W2^T) ) ----------------
template<int K>
__device__ __forceinline__ void gemm_pass(const float* __restrict__ A, const float* __restrict__ W,
                                          float* As, float* Wsh, float (&acc)[2][4],
                                          int bt, int ot, int tid)
{
    int tx = tid & 15, ty = tid >> 4;
    for (int kt = 0; kt < K/32; kt++){
        {
            int bb = tid >> 3, kk = (tid & 7) * 4;
            float4 v = *(const float4*)(A + (bt*32+bb)*K + kt*32 + kk);
            float* ap = As + bb*33 + kk;
            ap[0]=v.x; ap[1]=v.y; ap[2]=v.z; ap[3]=v.w;
        }
        {
            int oo = tid >> 2, kk = (tid & 3) * 8;
            const float* g = W + (ot*64+oo)*K + kt*32 + kk;
            float4 v0 = *(const float4*)g;
            float4 v1 = *(const float4*)(g + 4);
            float* wp = Wsh + oo*33 + kk;
            wp[0]=v0.x; wp[1]=v0.y; wp[2]=v0.z; wp[3]=v0.w;
            wp[4]=v1.x; wp[5]=v1.y; wp[6]=v1.z; wp[7]=v1.w;
        }
        __syncthreads();
        #pragma unroll
        for (int kk = 0; kk < 32; kk++){
            float a0 = As[(ty*2)*33 + kk], a1 = As[(ty*2+1)*33 + kk];
            float w0 = Wsh[(tx*4)*33+kk],   w1 = Wsh[(tx*4+1)*33+kk];
            float w2 = Wsh[(tx*4+2)*33+kk], w3 = Wsh[(tx*4+3)*33+kk];
            acc[0][0] += a0*w0; acc[0][1] += a0*w1; acc[0][2] += a0*w2; acc[0][3] += a0*w3;
            acc[1][0] += a1*w0; acc[1][1] += a1*w1; acc[1][2] += a1*w2; acc[1][3] += a1*w3;
        }
        __syncthreads();
    }
}

template<int K1, int K2, int RELU>
__global__ __launch_bounds__(256) void k_gemm(const float* __restrict__ A1, const float* __restrict__ W1,
                                              const float* __restrict__ A2, const float* __restrict__ W2,
                                              float* __restrict__ C, int Osz)
{
    __shared__ float As[32*33];
    __shared__ float Wsh[64*33];
    int tid = threadIdx.x, tx = tid & 15, ty = tid >> 4;
    int ot = blockIdx.x, bt = blockIdx.y;
    float acc[2][4];
    #pragma unroll
    for (int i=0;i<2;i++){
        #pragma unroll
        for (int j=0;j<4;j++) acc[i][j]=0.f;
    }
    gemm_pass<K1>(A1, W1, As, Wsh, acc, bt, ot, tid);
    if constexpr (K2 > 0){
        gemm_pass<K2>(A2, W2, As, Wsh, acc, bt, ot, tid);
    }
    #pragma unroll
    for (int i=0;i<2;i++){
        float4 v;
        v.x = acc[i][0]; v.y = acc[i][1]; v.z = acc[i][2]; v.w = acc[i][3];
        if (RELU){ v.x=fmaxf(v.x,0.f); v.y=fmaxf(v.y,0.f); v.z=fmaxf(v.z,0.f); v.w=fmaxf(v.w,0.f); }
        *(float4*)(C + (bt*32+ty*2+i)*Osz + ot*64 + tx*4) = v;
    }
}

// fused two head GEMMs: blockIdx.x<4 -> Wm1 chunk -> TM; >=4 -> Wv1 chunk -> TV
__global__ __launch_bounds__(256) void k_heads2(const float* __restrict__ A, const float* __restrict__ Wm1,
                                                const float* __restrict__ Wv1, float* __restrict__ ws)
{
    __shared__ float As[32*33];
    __shared__ float Wsh[64*33];
    int tid = threadIdx.x, tx = tid & 15, ty = tid >> 4;
    int bx = blockIdx.x, bt = blockIdx.y;
    int ot = bx & 3;
    const float* W = (bx < 4) ? Wm1 : Wv1;
    float* C = ws + ((bx < 4) ? OFF_TM : OFF_TV);
    float acc[2][4];
    #pragma unroll
    for (int i=0;i<2;i++){
        #pragma unroll
        for (int j=0;j<4;j++) acc[i][j]=0.f;
    }
    gemm_pass<256>(A, W, As, Wsh, acc, bt, ot, tid);
    #pragma unroll
    for (int i=0;i<2;i++){
        float4 v;
        v.x = fmaxf(acc[i][0],0.f); v.y = fmaxf(acc[i][1],0.f);
        v.z = fmaxf(acc[i][2],0.f); v.w = fmaxf(acc[i][3],0.f);
        *(float4*)(C + (bt*32+ty*2+i)*256 + ot*64 + tx*4) = v;
    }
}

// ---------------- LSTM gate elementwise (layer 0) ----------------
__global__ __launch_bounds__(256) void k_gates(float* __restrict__ ws, int l)
{
    int b = blockIdx.x, t = threadIdx.x;
    const float* g = ws + OFF_GB + b*1024;
    float ig = g[t], fg = g[256+t], gg = g[512+t], og = g[768+t];
    int idx = l*BB*256 + b*256 + t;
    float cold = ws[OFF_C + idx];
    float cl = sigf(fg)*cold + sigf(ig)*tanhf(gg);
    float hl = sigf(og)*tanhf(cl);
    ws[OFF_C + idx] = cl;
    ws[OFF_H + idx] = hl;
}

// fused: layer-1 gates + LN(h1) + relu -> rmn  (one block per b: safe single writer)
__global__ __launch_bounds__(256) void k_mn(float* __restrict__ ws)
{
    __shared__ float rbuf[4];
    int b = blockIdx.x, t = threadIdx.x;
    const float* g = ws + OFF_GB + b*1024;
    float ig = g[t], fg = g[256+t], gg = g[512+t], og = g[768+t];
    int idx = BB*256 + b*256 + t;
    float cold = ws[OFF_C + idx];
    float cl = sigf(fg)*cold + sigf(ig)*tanhf(gg);
    float hl = sigf(og)*tanhf(cl);
    ws[OFF_C + idx] = cl;
    ws[OFF_H + idx] = hl;
    float mu = blockSum256(hl, rbuf) * (1.0f/256.0f);
    float d = hl - mu;
    float var = blockSum256(d*d, rbuf) * (1.0f/256.0f);
    ws[OFF_RMN + b*256 + t] = fmaxf(d * rsqrtf(var + 1e-5f), 0.0f);
}

// heads: mean/var 3-vec each; updates anchor and writes outputs
__global__ __launch_bounds__(256) void k_head(const float* __restrict__ Wm2, const float* __restrict__ Wv2,
                                              const float* __restrict__ dlm, float* __restrict__ ws,
                                              float* __restrict__ out, int s, int t)
{
    int b = blockIdx.x, tid = threadIdx.x;
    int w = tid >> 6, lane = tid & 63;
    #pragma unroll
    for (int p = 0; p < 2; p++){
        int oi = p*4 + w;
        if (oi < 6){
            int j = (oi < 3) ? oi : oi - 3;
            const float* tb = ws + ((oi < 3) ? OFF_TM : OFF_TV) + b*256;
            const float* wr = ((oi < 3) ? Wm2 : Wv2) + j*256;
            float pa = 0.f;
            #pragma unroll
            for (int q = 0; q < 4; q++) pa += tb[lane + 64*q] * wr[lane + 64*q];
            for (int off = 32; off > 0; off >>= 1) pa += __shfl_down(pa, off, 64);
            if (lane == 0){
                if (oi < 3){
                    float mv = tanhf(pa) * dlm[j] + ws[OFF_ANCHOR + b*3 + j];
                    out[((b*NSTEP + s)*5 + (t+1))*3 + j] = mv;
                    ws[OFF_ANCHOR + b*3 + j] = mv;
                } else {
                    out[OUT_VAR + ((b*NSTEP + s)*5 + (t+1))*3 + j] = sigf(pa)*0.1f;
                }
            }
        }
    }
}

extern "C" void kernel_launch(void* const* d_in, const int* in_sizes, int n_in,
                              void* d_out, int out_size, void* d_ws, size_t ws_size,
                              hipStream_t stream)
{
    (void)in_sizes; (void)n_in; (void)out_size; (void)ws_size;
    const float* inp  = (const float*)d_in[0];
    const float* mp   = (const float*)d_in[1];
    const float* endp = (const float*)d_in[2];
    const float* dlm  = (const float*)d_in[3];
    const float* Wenc = (const float*)d_in[4];
    const float* Wq   = (const float*)d_in[5];
    const float* Wk   = (const float*)d_in[6];
    const float* Wv   = (const float*)d_in[7];
    const float* Win  = (const float*)d_in[8];
    const float* Wout = (const float*)d_in[9];
    const float* Wmap1= (const float*)d_in[10];
    const float* Wmap2= (const float*)d_in[11];
    const float* Wih0 = (const float*)d_in[12];
    const float* Wih1 = (const float*)d_in[13];
    const float* Whh0 = (const float*)d_in[14];
    const float* Whh1 = (const float*)d_in[15];
    const float* Wm1  = (const float*)d_in[16];
    const float* Wm2  = (const float*)d_in[17];
    const float* Wv1  = (const float*)d_in[18];
    const float* Wv2  = (const float*)d_in[19];
    float* out = (float*)d_out;
    float* ws  = (float*)d_ws;

    k_init<<<2, 256, 0, stream>>>(inp, ws);
    k_pre<<<NSTEP, 256, 0, stream>>>(Wq, Wk, Wv, Win, Wout, ws);
    for (int s = 0; s < NSTEP; s++){
        k_step_init<<<256, 256, 0, stream>>>(ws, out, s);
        for (int t = 0; t < NITER; t++){
            k_map<<<BB, 256, 0, stream>>>(mp, ws, out, s, t);
            k_encattn<<<BB, 256, 0, stream>>>(out, ws, Wenc, endp, s, t);
            k_big<<<dim3(4, 4, BB), 256, 0, stream>>>(ws, Wmap1 + s*65536, Wmap2 + s*256, s);
            k_lnencm<<<BB, 256, 0, stream>>>(ws);
            k_gemm<512,256,0><<<dim3(16,4), 256, 0, stream>>>(ws+OFF_XL, Wih0 + s*524288,
                                                              ws+OFF_H,  Whh0 + s*262144,
                                                              ws+OFF_GB, 1024);
            k_gates<<<BB, 256, 0, stream>>>(ws, 0);
            k_gemm<256,256,0><<<dim3(16,4), 256, 0, stream>>>(ws+OFF_H,          Wih1 + s*262144,
                                                              ws+OFF_H + BB*256, Whh1 + s*262144,
                                                              ws+OFF_GB, 1024);
            k_mn<<<BB, 256, 0, stream>>>(ws);
            k_heads2<<<dim3(8,4), 256, 0, stream>>>(ws+OFF_RMN, Wm1 + s*65536, Wv1 + s*65536, ws);
            k_head<<<BB, 256, 0, stream>>>(Wm2 + s*768, Wv2 + s*768, dlm, ws, out, s, t);
        }
        k_map<<<BB, 256, 0, stream>>>(mp, ws, out, s, 4);
    }
}